// Round 13
// baseline (179.706 us; speedup 1.0000x reference)
//
#include <hip/hip_runtime.h>
#include <hip/hip_cooperative_groups.h>

namespace cg = cooperative_groups;

#define N_NODES 1536
#define IN_F    1433
#define HID     64
#define NH      8
#define HF      8
#define NC      7
#define MAXN    64          // true max degree ~35
#define GST     66          // padded LDS row stride (2-way bank aliasing = free)
#define G1_BLOCKS 384
#define ROWS    4
#define XS_STRIDE 1440
#define P23_GRID 768        // 768 blocks x 2 waves = 1536 = one node per wave
#define PSZ     4816        // per-wave LDS region (floats): max(attn1 4816, back 4800)

__device__ __forceinline__ float waveAllMax(float v) {
#pragma unroll
    for (int o = 32; o > 0; o >>= 1) v = fmaxf(v, __shfl_xor(v, o, 64));
    return v;
}
__device__ __forceinline__ float waveAllSum(float v) {
#pragma unroll
    for (int o = 32; o > 0; o >>= 1) v += __shfl_xor(v, o, 64);
    return v;
}

// ================= shared device bodies (R11/R12-proven logic) =================

// 256-thread unit: g1 rows [u*4, u*4+4) = x @ W1. xs: 5760 floats, red: 1024 floats.
__device__ __forceinline__ void gemm1_unit(int u, const float* __restrict__ x,
                                           const float* __restrict__ W1,
                                           float* __restrict__ g1,
                                           float* xs, float* red) {
    const int t = threadIdx.x;
    const int i0 = u * ROWS;
    for (int r = 0; r < ROWS; ++r) {
        const float* xr = x + (size_t)(i0 + r) * IN_F;
        for (int k = t; k < XS_STRIDE; k += 256)
            xs[r * XS_STRIDE + k] = (k < IN_F) ? xr[k] : 0.f;
    }
    __syncthreads();
    const int j = t & 63, q = t >> 6;
    float acc[ROWS] = {0.f, 0.f, 0.f, 0.f};
    const int k0 = q * 360;
    for (int kb = k0; kb < k0 + 360; kb += 4) {
        float w[4];
#pragma unroll
        for (int u2 = 0; u2 < 4; ++u2) {
            int k = kb + u2;
            int kc = (k < IN_F) ? k : (IN_F - 1);   // clamp; xs pad is 0
            w[u2] = W1[(size_t)kc * HID + j];
        }
#pragma unroll
        for (int r = 0; r < ROWS; ++r) {
            float4 xv = *(const float4*)(xs + r * XS_STRIDE + kb);
            acc[r] += xv.x * w[0] + xv.y * w[1] + xv.z * w[2] + xv.w * w[3];
        }
    }
#pragma unroll
    for (int r = 0; r < ROWS; ++r) red[q * 256 + r * 64 + j] = acc[r];
    __syncthreads();
    float s = red[0 * 256 + t] + red[1 * 256 + t] + red[2 * 256 + t] + red[3 * 256 + t];
    g1[(size_t)(i0 + (t >> 6)) * HID + (t & 63)] = s;
}

// 256-thread unit: compact adj row i (int32 elements, uint4-vectorized).
__device__ __forceinline__ void compact_unit(int i, const uint4* __restrict__ adjv,
                                             int* __restrict__ cnt, int* __restrict__ nbr,
                                             int* lc) {
    const int t = threadIdx.x;
    if (t == 0) *lc = 0;
    __syncthreads();
    const uint4* row = adjv + (size_t)i * (N_NODES / 4);
    for (int v = t; v < N_NODES / 4; v += 256) {
        uint4 q = row[v];
        unsigned int c[4] = {q.x, q.y, q.z, q.w};
#pragma unroll
        for (int b = 0; b < 4; ++b) {
            if (c[b] != 0u) {
                int p = atomicAdd(lc, 1);
                if (p < MAXN) nbr[i * MAXN + p] = v * 4 + b;
            }
        }
    }
    __syncthreads();
    if (t == 0) {
        int n = (*lc > MAXN) ? MAXN : *lc;
        if (n == 0) { nbr[i * MAXN] = i; n = 1; }   // diagonal always set in ref
        cnt[i] = n;
    }
}

// one-wave unit: layer-1 attention + ELU for node i. P: 4816 floats.
// All __syncthreads() call sites are block-uniform.
__device__ __forceinline__ void attn1_node(int i, int lane, const float* __restrict__ g1,
                                           const int* __restrict__ cnt,
                                           const int* __restrict__ nbr,
                                           const float* __restrict__ a1,
                                           float* __restrict__ h1, float* P) {
    float* gis = P;                    // 64
    float* gj  = P + 64;               // MAXN*GST = 4224
    float* es  = P + 64 + MAXN * GST;  // NH*GST = 528
    const int n = cnt[i];

    gis[lane] = g1[(size_t)i * HID + lane];            // coalesced
    const int jn = nbr[i * MAXN + lane];               // slot lane (unused if >= n)
    for (int l = 0; l < n; ++l) {
        int j = __shfl(jn, l, 64);                     // broadcast slot l's neighbor
        gj[l * GST + lane] = g1[(size_t)j * HID + lane];  // coalesced 256B row
    }
    __syncthreads();

    float av[HF];
#pragma unroll
    for (int f = 0; f < HF; ++f) av[f] = a1[f];

    float sc[NH];
    if (lane < n) {
#pragma unroll
        for (int h = 0; h < NH; ++h) {
            float s = 0.f;
#pragma unroll
            for (int f = 0; f < HF; ++f) {
                float v = gis[h * HF + f] + gj[lane * GST + h * HF + f];
                v = (v >= 0.f) ? v : 0.2f * v;         // leaky_relu 0.2
                s += av[f] * v;
            }
            sc[h] = s;
        }
    } else {
#pragma unroll
        for (int h = 0; h < NH; ++h) sc[h] = -INFINITY;
    }

    float S[NH];
#pragma unroll
    for (int h = 0; h < NH; ++h) {
        float m = waveAllMax(sc[h]);
        float p = (lane < n) ? __expf(sc[h] - m) : 0.f;
        es[h * GST + lane] = p;
        S[h] = waveAllSum(p);
    }
    __syncthreads();

    const int h = lane >> 3;                           // lane = output column
    float acc = 0.f;
    for (int l = 0; l < n; ++l)
        acc += es[h * GST + l] * gj[l * GST + lane];
    acc /= S[h];
    h1[(size_t)i * HID + lane] = (acc > 0.f) ? acc : (__expf(acc) - 1.f);  // ELU
}

// one-wave unit: g2 = h1@W2 for N(i) + layer-2 attention, f32 out. Q: 4800 floats.
__device__ __forceinline__ void back_node(int i, int lane, const float* __restrict__ h1,
                                          const float* __restrict__ a2,
                                          const int* __restrict__ cnt,
                                          const int* __restrict__ nbr,
                                          float* __restrict__ out,
                                          float* Q, const float* w2s) {
    float* hj  = Q;                    // MAXN*GST = 4224
    float* g2s = Q + MAXN * GST;       // MAXN*8 = 512
    float* ps  = Q + MAXN * GST + MAXN * 8;   // 64
    const int n = cnt[i];

    const int jn = nbr[i * MAXN + lane];
    for (int l = 0; l < n; ++l) {
        int j = __shfl(jn, l, 64);
        hj[l * GST + lane] = h1[(size_t)j * HID + lane];   // coalesced
    }
    __syncthreads();

    if (lane < n) {
#pragma unroll
        for (int c = 0; c < NC; ++c) {
            float s = 0.f;
            for (int f = 0; f < HID; ++f)
                s += hj[lane * GST + f] * w2s[f * NC + c];
            g2s[lane * 8 + c] = s;
        }
    }
    // self slot (diagonal guaranteed in neighbor list)
    unsigned long long bal = __ballot(lane < n && jn == i);
    int ls = (bal != 0ull) ? (__ffsll((long long)bal) - 1) : 0;
    __syncthreads();

    float scv;
    if (lane < n) {
        float s = 0.f;
#pragma unroll
        for (int c = 0; c < NC; ++c) {
            float v = g2s[ls * 8 + c] + g2s[lane * 8 + c];
            v = (v >= 0.f) ? v : 0.2f * v;
            s += a2[c] * v;
        }
        scv = s;
    } else scv = -INFINITY;

    float m = waveAllMax(scv);
    float p = (lane < n) ? __expf(scv - m) : 0.f;
    ps[lane] = p;
    float S = waveAllSum(p);
    __syncthreads();

    if (lane < NC) {
        float acc = 0.f;
        for (int l = 0; l < n; ++l)
            acc += ps[l] * g2s[l * 8 + lane];
        out[(size_t)i * NC + lane] = acc / S;          // mean over 1 head = identity
    }
}

// ================= dispatch kernels =================

// K1 (normal launch, high occupancy): gemm1 (384 blocks) + compact (1536 blocks)
__global__ __launch_bounds__(256) void k_front(const float* __restrict__ x,
                                               const float* __restrict__ W1,
                                               const uint4* __restrict__ adjv,
                                               float* __restrict__ g1,
                                               int* __restrict__ cnt,
                                               int* __restrict__ nbr) {
    __shared__ float xs[ROWS * XS_STRIDE];
    __shared__ float red[4 * 256];
    __shared__ int lc;
    if (blockIdx.x < G1_BLOCKS) gemm1_unit(blockIdx.x, x, W1, g1, xs, red);
    else                        compact_unit(blockIdx.x - G1_BLOCKS, adjv, cnt, nbr, &lc);
}

// K2 (cooperative): attn1 -> grid.sync -> gemm2+attn2. 2 waves/block, one node/wave.
// LDS: 2*4816 + 448 = 10080 floats = 40.3 KB -> 3 blocks/CU -> 768 co-resident.
__global__ __launch_bounds__(128) void k_p23(const float* __restrict__ g1,
                                             const int* __restrict__ cnt,
                                             const int* __restrict__ nbr,
                                             const float* __restrict__ a1,
                                             const float* __restrict__ W2,
                                             const float* __restrict__ a2,
                                             float* __restrict__ h1,
                                             float* __restrict__ out) {
    __shared__ float lds[2 * PSZ + HID * NC];
    cg::grid_group grid = cg::this_grid();
    const int t = threadIdx.x, w = t >> 6, lane = t & 63;
    const int i = blockIdx.x * 2 + w;                  // in [0, 1536) exactly

    attn1_node(i, lane, g1, cnt, nbr, a1, h1, lds + w * PSZ);
    grid.sync();

    float* w2s = lds + 2 * PSZ;
    for (int k = t; k < HID * NC; k += 128) w2s[k] = W2[k];
    // back_node's first __syncthreads() orders w2s before its use
    back_node(i, lane, h1, a2, cnt, nbr, out, lds + w * PSZ, w2s);
}

// fallback kernels (R11-proven 2-dispatch tail)
__global__ __launch_bounds__(64) void k_attn1(const float* __restrict__ g1,
                                              const int* __restrict__ cnt,
                                              const int* __restrict__ nbr,
                                              const float* __restrict__ a1,
                                              float* __restrict__ h1) {
    __shared__ float P[PSZ];
    attn1_node(blockIdx.x, threadIdx.x, g1, cnt, nbr, a1, h1, P);
}

__global__ __launch_bounds__(64) void k_back(const float* __restrict__ h1,
                                             const float* __restrict__ W2,
                                             const float* __restrict__ a2,
                                             const int* __restrict__ cnt,
                                             const int* __restrict__ nbr,
                                             float* __restrict__ out) {
    __shared__ float Q[PSZ];
    __shared__ float w2s[HID * NC];
    for (int k = threadIdx.x; k < HID * NC; k += 64) w2s[k] = W2[k];
    back_node(blockIdx.x, threadIdx.x, h1, a2, cnt, nbr, out, Q, w2s);
}

extern "C" void kernel_launch(void* const* d_in, const int* in_sizes, int n_in,
                              void* d_out, int out_size, void* d_ws, size_t ws_size,
                              hipStream_t stream) {
    (void)out_size; (void)ws_size;
    // input identity by element count (robust to ordering; proven R8/R11)
    const void* px = nullptr; const void* padj = nullptr;
    const void* pW1 = nullptr; const void* pa1 = nullptr;
    const void* pW2 = nullptr; const void* pa2 = nullptr;
    for (int i = 0; i < n_in; ++i) {
        switch (in_sizes[i]) {
            case N_NODES * IN_F:    px   = d_in[i]; break;
            case N_NODES * N_NODES: padj = d_in[i]; break;
            case IN_F * HID:        pW1  = d_in[i]; break;
            case HF:                pa1  = d_in[i]; break;
            case HID * NC:          pW2  = d_in[i]; break;
            case NC:                pa2  = d_in[i]; break;
            default: break;
        }
    }
    if (!px && n_in > 0)   px   = d_in[0];
    if (!padj && n_in > 1) padj = d_in[1];
    if (!pW1 && n_in > 2)  pW1  = d_in[2];
    if (!pa1 && n_in > 3)  pa1  = d_in[3];
    if (!pW2 && n_in > 4)  pW2  = d_in[4];
    if (!pa2 && n_in > 5)  pa2  = d_in[5];

    char* w = (char*)d_ws;
    size_t off = 0;
    auto carve = [&](size_t bytes) -> char* {
        off = (off + 255) & ~(size_t)255;
        char* p = w + off; off += bytes; return p;
    };
    int*   cnt = (int*)  carve((size_t)N_NODES * 4);
    int*   nbr = (int*)  carve((size_t)N_NODES * MAXN * 4);
    float* g1  = (float*)carve((size_t)N_NODES * HID * 4);
    float* h1  = (float*)carve((size_t)N_NODES * HID * 4);

    const float* xf   = (const float*)px;
    const float* W1f  = (const float*)pW1;
    const uint4* adjv = (const uint4*)padj;
    const float* a1f  = (const float*)pa1;
    const float* W2f  = (const float*)pW2;
    const float* a2f  = (const float*)pa2;
    float* outp       = (float*)d_out;   // reference output dtype: float32

    k_front<<<G1_BLOCKS + N_NODES, 256, 0, stream>>>(xf, W1f, adjv, g1, cnt, nbr);

    // deterministic host-side capability check (same result every call)
    int dev = 0; (void)hipGetDevice(&dev);
    int coop = 0;
    (void)hipDeviceGetAttribute(&coop, hipDeviceAttributeCooperativeLaunch, dev);
    int maxb = 0;
    if (coop)
        (void)hipOccupancyMaxActiveBlocksPerMultiprocessor(&maxb, (const void*)k_p23, 128, 0);

    bool done = false;
    if (coop && maxb >= 3) {   // need 768 co-resident blocks (3/CU x 256 CUs)
        const float* g1c = g1; const int* cntc = cnt; const int* nbrc = nbr;
        float* h1m = h1;
        void* args[] = { (void*)&g1c, (void*)&cntc, (void*)&nbrc, (void*)&a1f,
                         (void*)&W2f, (void*)&a2f, (void*)&h1m, (void*)&outp };
        hipError_t e = hipLaunchCooperativeKernel((const void*)k_p23, dim3(P23_GRID),
                                                  dim3(128), args, 0, stream);
        done = (e == hipSuccess);
    }
    if (!done) {
        k_attn1<<<N_NODES, 64, 0, stream>>>(g1, cnt, nbr, a1f, h1);
        k_back<<<N_NODES, 64, 0, stream>>>(h1, W2f, a2f, cnt, nbr, outp);
    }
}

// Round 15
// 131.741 us; speedup vs baseline: 1.3641x; 1.3641x over previous
//
#include <hip/hip_runtime.h>

#define N_NODES 1536
#define IN_F    1433
#define HID     64
#define NH      8
#define HF      8
#define NC      7
#define MAXN    64          // true max degree ~35
#define GST     66          // padded LDS row stride (2-way bank aliasing = free)
#define G1_BLOCKS 384
#define ROWS    4
#define XS_STRIDE 1440
#define PSZ     4816        // per-wave LDS region (floats): max(attn1 4816, back 4800)

__device__ __forceinline__ float waveAllMax(float v) {
#pragma unroll
    for (int o = 32; o > 0; o >>= 1) v = fmaxf(v, __shfl_xor(v, o, 64));
    return v;
}
__device__ __forceinline__ float waveAllSum(float v) {
#pragma unroll
    for (int o = 32; o > 0; o >>= 1) v += __shfl_xor(v, o, 64);
    return v;
}

// ================= shared device bodies (R11/R13-proven logic) =================

// 256-thread unit: g1 rows [u*4, u*4+4) = x @ W1.
__device__ __forceinline__ void gemm1_unit(int u, const float* __restrict__ x,
                                           const float* __restrict__ W1,
                                           float* __restrict__ g1,
                                           float* xs, float* red) {
    const int t = threadIdx.x;
    const int i0 = u * ROWS;
    for (int r = 0; r < ROWS; ++r) {
        const float* xr = x + (size_t)(i0 + r) * IN_F;
        for (int k = t; k < XS_STRIDE; k += 256)
            xs[r * XS_STRIDE + k] = (k < IN_F) ? xr[k] : 0.f;
    }
    __syncthreads();
    const int j = t & 63, q = t >> 6;
    float acc[ROWS] = {0.f, 0.f, 0.f, 0.f};
    const int k0 = q * 360;
    for (int kb = k0; kb < k0 + 360; kb += 4) {
        float w[4];
#pragma unroll
        for (int u2 = 0; u2 < 4; ++u2) {
            int k = kb + u2;
            int kc = (k < IN_F) ? k : (IN_F - 1);   // clamp; xs pad is 0
            w[u2] = W1[(size_t)kc * HID + j];
        }
#pragma unroll
        for (int r = 0; r < ROWS; ++r) {
            float4 xv = *(const float4*)(xs + r * XS_STRIDE + kb);
            acc[r] += xv.x * w[0] + xv.y * w[1] + xv.z * w[2] + xv.w * w[3];
        }
    }
#pragma unroll
    for (int r = 0; r < ROWS; ++r) red[q * 256 + r * 64 + j] = acc[r];
    __syncthreads();
    float s = red[0 * 256 + t] + red[1 * 256 + t] + red[2 * 256 + t] + red[3 * 256 + t];
    g1[(size_t)(i0 + (t >> 6)) * HID + (t & 63)] = s;
}

// 256-thread unit: compact adj row i (int32 elements, uint4-vectorized; proven R13).
__device__ __forceinline__ void compact_unit(int i, const uint4* __restrict__ adjv,
                                             int* __restrict__ cnt, int* __restrict__ nbr,
                                             int* lc) {
    const int t = threadIdx.x;
    if (t == 0) *lc = 0;
    __syncthreads();
    const uint4* row = adjv + (size_t)i * (N_NODES / 4);
    for (int v = t; v < N_NODES / 4; v += 256) {
        uint4 q = row[v];
        unsigned int c[4] = {q.x, q.y, q.z, q.w};
#pragma unroll
        for (int b = 0; b < 4; ++b) {
            if (c[b] != 0u) {
                int p = atomicAdd(lc, 1);
                if (p < MAXN) nbr[i * MAXN + p] = v * 4 + b;
            }
        }
    }
    __syncthreads();
    if (t == 0) {
        int n = (*lc > MAXN) ? MAXN : *lc;
        if (n == 0) { nbr[i * MAXN] = i; n = 1; }   // diagonal always set in ref
        cnt[i] = n;
    }
}

// one-wave unit: layer-1 attention + ELU for node i. P: 4816 floats.
__device__ __forceinline__ void attn1_node(int i, int lane, const float* __restrict__ g1,
                                           const int* __restrict__ cnt,
                                           const int* __restrict__ nbr,
                                           const float* __restrict__ a1,
                                           float* __restrict__ h1, float* P) {
    float* gis = P;                    // 64
    float* gj  = P + 64;               // MAXN*GST = 4224
    float* es  = P + 64 + MAXN * GST;  // NH*GST = 528
    const int n = cnt[i];

    gis[lane] = g1[(size_t)i * HID + lane];            // coalesced
    const int jn = nbr[i * MAXN + lane];               // slot lane (unused if >= n)
    for (int l = 0; l < n; ++l) {
        int j = __shfl(jn, l, 64);                     // broadcast slot l's neighbor
        gj[l * GST + lane] = g1[(size_t)j * HID + lane];  // coalesced 256B row
    }
    __syncthreads();

    float av[HF];
#pragma unroll
    for (int f = 0; f < HF; ++f) av[f] = a1[f];

    float sc[NH];
    if (lane < n) {
#pragma unroll
        for (int h = 0; h < NH; ++h) {
            float s = 0.f;
#pragma unroll
            for (int f = 0; f < HF; ++f) {
                float v = gis[h * HF + f] + gj[lane * GST + h * HF + f];
                v = (v >= 0.f) ? v : 0.2f * v;         // leaky_relu 0.2
                s += av[f] * v;
            }
            sc[h] = s;
        }
    } else {
#pragma unroll
        for (int h = 0; h < NH; ++h) sc[h] = -INFINITY;
    }

    float S[NH];
#pragma unroll
    for (int h = 0; h < NH; ++h) {
        float m = waveAllMax(sc[h]);
        float p = (lane < n) ? __expf(sc[h] - m) : 0.f;
        es[h * GST + lane] = p;
        S[h] = waveAllSum(p);
    }
    __syncthreads();

    const int h = lane >> 3;                           // lane = output column
    float acc = 0.f;
    for (int l = 0; l < n; ++l)
        acc += es[h * GST + l] * gj[l * GST + lane];
    acc /= S[h];
    h1[(size_t)i * HID + lane] = (acc > 0.f) ? acc : (__expf(acc) - 1.f);  // ELU
}

// one-wave unit: g2 = h1@W2 for N(i) + layer-2 attention, f32 out. Q: 4800 floats.
__device__ __forceinline__ void back_node(int i, int lane, const float* __restrict__ h1,
                                          const float* __restrict__ a2,
                                          const int* __restrict__ cnt,
                                          const int* __restrict__ nbr,
                                          float* __restrict__ out,
                                          float* Q, const float* w2s) {
    float* hj  = Q;                    // MAXN*GST = 4224
    float* g2s = Q + MAXN * GST;       // MAXN*8 = 512
    float* ps  = Q + MAXN * GST + MAXN * 8;   // 64
    const int n = cnt[i];

    const int jn = nbr[i * MAXN + lane];
    for (int l = 0; l < n; ++l) {
        int j = __shfl(jn, l, 64);
        hj[l * GST + lane] = h1[(size_t)j * HID + lane];   // coalesced
    }
    __syncthreads();

    if (lane < n) {
#pragma unroll
        for (int c = 0; c < NC; ++c) {
            float s = 0.f;
            for (int f = 0; f < HID; ++f)
                s += hj[lane * GST + f] * w2s[f * NC + c];
            g2s[lane * 8 + c] = s;
        }
    }
    // self slot (diagonal guaranteed in neighbor list)
    unsigned long long bal = __ballot(lane < n && jn == i);
    int ls = (bal != 0ull) ? (__ffsll((long long)bal) - 1) : 0;
    __syncthreads();

    float scv;
    if (lane < n) {
        float s = 0.f;
#pragma unroll
        for (int c = 0; c < NC; ++c) {
            float v = g2s[ls * 8 + c] + g2s[lane * 8 + c];
            v = (v >= 0.f) ? v : 0.2f * v;
            s += a2[c] * v;
        }
        scv = s;
    } else scv = -INFINITY;

    float m = waveAllMax(scv);
    float p = (lane < n) ? __expf(scv - m) : 0.f;
    ps[lane] = p;
    float S = waveAllSum(p);
    __syncthreads();

    if (lane < NC) {
        float acc = 0.f;
        for (int l = 0; l < n; ++l)
            acc += ps[l] * g2s[l * 8 + lane];
        out[(size_t)i * NC + lane] = acc / S;          // mean over 1 head = identity
    }
}

// ================= dispatch kernels (R11 structure, proven) =================

__global__ __launch_bounds__(256) void k_front(const float* __restrict__ x,
                                               const float* __restrict__ W1,
                                               const uint4* __restrict__ adjv,
                                               float* __restrict__ g1,
                                               int* __restrict__ cnt,
                                               int* __restrict__ nbr) {
    __shared__ float xs[ROWS * XS_STRIDE];
    __shared__ float red[4 * 256];
    __shared__ int lc;
    if (blockIdx.x < G1_BLOCKS) gemm1_unit(blockIdx.x, x, W1, g1, xs, red);
    else                        compact_unit(blockIdx.x - G1_BLOCKS, adjv, cnt, nbr, &lc);
}

__global__ __launch_bounds__(64) void k_attn1(const float* __restrict__ g1,
                                              const int* __restrict__ cnt,
                                              const int* __restrict__ nbr,
                                              const float* __restrict__ a1,
                                              float* __restrict__ h1) {
    __shared__ float P[PSZ];
    attn1_node(blockIdx.x, threadIdx.x, g1, cnt, nbr, a1, h1, P);
}

__global__ __launch_bounds__(64) void k_back(const float* __restrict__ h1,
                                             const float* __restrict__ W2,
                                             const float* __restrict__ a2,
                                             const int* __restrict__ cnt,
                                             const int* __restrict__ nbr,
                                             float* __restrict__ out) {
    __shared__ float Q[PSZ];
    __shared__ float w2s[HID * NC];
    for (int k = threadIdx.x; k < HID * NC; k += 64) w2s[k] = W2[k];
    // back_node's first __syncthreads() orders w2s before its use
    back_node(blockIdx.x, threadIdx.x, h1, a2, cnt, nbr, out, Q, w2s);
}

extern "C" void kernel_launch(void* const* d_in, const int* in_sizes, int n_in,
                              void* d_out, int out_size, void* d_ws, size_t ws_size,
                              hipStream_t stream) {
    (void)out_size; (void)ws_size;
    // input identity by element count (robust to ordering; proven R8/R11)
    const void* px = nullptr; const void* padj = nullptr;
    const void* pW1 = nullptr; const void* pa1 = nullptr;
    const void* pW2 = nullptr; const void* pa2 = nullptr;
    for (int i = 0; i < n_in; ++i) {
        switch (in_sizes[i]) {
            case N_NODES * IN_F:    px   = d_in[i]; break;
            case N_NODES * N_NODES: padj = d_in[i]; break;
            case IN_F * HID:        pW1  = d_in[i]; break;
            case HF:                pa1  = d_in[i]; break;
            case HID * NC:          pW2  = d_in[i]; break;
            case NC:                pa2  = d_in[i]; break;
            default: break;
        }
    }
    if (!px && n_in > 0)   px   = d_in[0];
    if (!padj && n_in > 1) padj = d_in[1];
    if (!pW1 && n_in > 2)  pW1  = d_in[2];
    if (!pa1 && n_in > 3)  pa1  = d_in[3];
    if (!pW2 && n_in > 4)  pW2  = d_in[4];
    if (!pa2 && n_in > 5)  pa2  = d_in[5];

    char* w = (char*)d_ws;
    size_t off = 0;
    auto carve = [&](size_t bytes) -> char* {
        off = (off + 255) & ~(size_t)255;
        char* p = w + off; off += bytes; return p;
    };
    int*   cnt = (int*)  carve((size_t)N_NODES * 4);
    int*   nbr = (int*)  carve((size_t)N_NODES * MAXN * 4);
    float* g1  = (float*)carve((size_t)N_NODES * HID * 4);
    float* h1  = (float*)carve((size_t)N_NODES * HID * 4);

    const float* xf   = (const float*)px;
    const float* W1f  = (const float*)pW1;
    const uint4* adjv = (const uint4*)padj;
    const float* a1f  = (const float*)pa1;
    const float* W2f  = (const float*)pW2;
    const float* a2f  = (const float*)pa2;
    float* outp       = (float*)d_out;   // reference output dtype: float32

    k_front<<<G1_BLOCKS + N_NODES, 256, 0, stream>>>(xf, W1f, adjv, g1, cnt, nbr);
    k_attn1<<<N_NODES, 64, 0, stream>>>(g1, cnt, nbr, a1f, h1);
    k_back<<<N_NODES, 64, 0, stream>>>(h1, W2f, a2f, cnt, nbr, outp);
}